// Round 2
// baseline (138.394 us; speedup 1.0000x reference)
//
#include <hip/hip_runtime.h>

// Problem constants (fixed by the reference setup)
#define P_ 4
#define B_ 8
#define NPIX 65536      // H*W
#define G_ 4
#define C_ 12
#define NPAIR (C_ * B_) // 96
#define SLOT 24         // floats per (c,b) slot in global ws
#define LSLOT 23        // floats per class slot in LDS (odd -> classes hit distinct banks)
#define THREADS 256
#define PXT 2                       // pixels per thread
#define PXB (THREADS * PXT)         // 512 pixels per block
#define CHUNKS (NPIX / PXB)         // 128 chunks per batch
#define NBLK (B_ * CHUNKS)          // 1024 blocks

// ws layout per (c,b) pair: [0..15] = W[a][g], [16..19] = Z[a], [20] = count

__global__ __launch_bounds__(THREADS) void kld_accum_kernel(
    const float* __restrict__ act,     // [P, B, N, G]
    const int*   __restrict__ labels,  // [B, N]
    const float* __restrict__ gci,     // [P*G, C]
    float*       __restrict__ ws)      // [NPAIR][SLOT]
{
    __shared__ float s_acc[13 * LSLOT];   // 12 classes + 1 dummy (ignored label)
    __shared__ int   s_proj[13];
    const int t     = threadIdx.x;
    const int b     = blockIdx.x / CHUNKS;
    const int chunk = blockIdx.x % CHUNKS;

    for (int i = t; i < 13 * LSLOT; i += THREADS) s_acc[i] = 0.0f;
    if (t < C_) {
        // proj_idx[c] = argmax over rows of gci[:, c] (first max), then / G
        int best = 0; float bv = gci[t];
        #pragma unroll
        for (int r = 1; r < P_ * G_; ++r) {
            float v = gci[r * C_ + t];
            if (v > bv) { bv = v; best = r; }
        }
        s_proj[t] = best / G_;
    }
    if (t == C_) s_proj[C_] = 0;   // dummy class -> plane 0 (values discarded)
    __syncthreads();

    // pack proj table: 2 bits per class (P=4)
    unsigned table = 0;
    #pragma unroll
    for (int i = 0; i < 13; ++i) table |= ((unsigned)s_proj[i]) << (2 * i);

    const float* __restrict__ p0 = act + ((size_t)(0 * B_ + b)) * NPIX * G_;
    const float* __restrict__ p1 = act + ((size_t)(1 * B_ + b)) * NPIX * G_;
    const float* __restrict__ p2 = act + ((size_t)(2 * B_ + b)) * NPIX * G_;
    const float* __restrict__ p3 = act + ((size_t)(3 * B_ + b)) * NPIX * G_;
    const int*   __restrict__ lab = labels + (size_t)b * NPIX;
    const int n0 = chunk * PXB + t;

    #pragma unroll
    for (int j = 0; j < PXT; ++j) {
        const int n = n0 + j * THREADS;
        const int l = lab[n];
        // stream all 4 planes (fully coalesced 16B/lane), select in-register
        const float4 v0 = *reinterpret_cast<const float4*>(p0 + (size_t)n * G_);
        const float4 v1 = *reinterpret_cast<const float4*>(p1 + (size_t)n * G_);
        const float4 v2 = *reinterpret_cast<const float4*>(p2 + (size_t)n * G_);
        const float4 v3 = *reinterpret_cast<const float4*>(p3 + (size_t)n * G_);
        const int cef = ((unsigned)(l - 1) < (unsigned)C_) ? (l - 1) : C_;
        const int p   = (table >> (2 * cef)) & 3;
        const float4 v = (p == 0) ? v0 : (p == 1) ? v1 : (p == 2) ? v2 : v3;
        const float vv[4] = {v.x, v.y, v.z, v.w};
        float* slot = s_acc + cef * LSLOT;
        #pragma unroll
        for (int a = 0; a < 4; ++a) {
            const float e = __expf(vv[a]);
            atomicAdd(slot + 16 + a, e);          // Z_a
            #pragma unroll
            for (int g = 0; g < 4; ++g)
                atomicAdd(slot + a * 4 + g, e * vv[g]);  // W[a][g]
        }
        atomicAdd(slot + 20, 1.0f);               // count
    }
    __syncthreads();

    // flush block accumulators (classes 0..11 only) to global with atomics
    if (t < C_ * 21) {
        const int c = t / 21, i = t % 21;
        atomicAdd(ws + ((size_t)c * B_ + b) * SLOT + i, s_acc[c * LSLOT + i]);
    }
}

__global__ __launch_bounds__(128) void kld_finalize_kernel(
    const float* __restrict__ ws,     // [NPAIR][SLOT]
    const float* __restrict__ proto,  // [120, C]
    float*       __restrict__ out)
{
    __shared__ float s_tot[128];
    __shared__ float s_den[128];
    __shared__ float s_ok[C_];
    const int t = threadIdx.x;

    if (t < C_) {
        // proto_ok[c] = column sum > 0; 120 independent strided loads, unrolled
        float s = 0.0f;
        #pragma unroll
        for (int r = 0; r < 120; ++r) s += proto[r * C_ + t];
        s_ok[t] = s;
    }
    __syncthreads();

    float tot = 0.0f, den = 0.0f;
    if (t < NPAIR) {
        const int c = t / B_;
        const float* slot = ws + (size_t)t * SLOT;
        const float cnt = slot[20];
        if (s_ok[c] > 0.0f && cnt >= 2.0f) {
            float S[4][4];
            #pragma unroll
            for (int a = 0; a < 4; ++a) {
                const float zinv = 1.0f / slot[16 + a];
                #pragma unroll
                for (int g = 0; g < 4; ++g)
                    S[a][g] = slot[a * 4 + g] * zinv;
            }
            #pragma unroll
            for (int j = 0; j < 4; ++j)
                #pragma unroll
                for (int k = 0; k < 4; ++k)
                    if (k > j) {
                        const float kld = 0.5f * (S[j][j] + S[k][k] - S[j][k] - S[k][j]);
                        tot += __expf(-kld);
                    }
            den = 6.0f;   // G*(G-1)/2
        }
    }

    s_tot[t] = tot;
    s_den[t] = den;
    __syncthreads();
    #pragma unroll
    for (int s = 64; s >= 1; s >>= 1) {
        if (t < s) { s_tot[t] += s_tot[t + s]; s_den[t] += s_den[t + s]; }
        __syncthreads();
    }
    if (t == 0)
        out[0] = (s_den[0] > 0.0f) ? (s_tot[0] / s_den[0]) : 0.0f;
}

extern "C" void kernel_launch(void* const* d_in, const int* in_sizes, int n_in,
                              void* d_out, int out_size, void* d_ws, size_t ws_size,
                              hipStream_t stream) {
    const float* act    = (const float*)d_in[0];  // [P,B,N,G] fp32
    const int*   labels = (const int*)d_in[1];    // [B,H,W] int32
    const float* proto  = (const float*)d_in[2];  // [120, C] fp32
    const float* gci    = (const float*)d_in[3];  // [P*G, C] fp32
    float* out = (float*)d_out;
    float* ws  = (float*)d_ws;

    hipMemsetAsync(ws, 0, (size_t)NPAIR * SLOT * sizeof(float), stream);
    kld_accum_kernel<<<NBLK, THREADS, 0, stream>>>(act, labels, gci, ws);
    kld_finalize_kernel<<<1, 128, 0, stream>>>(ws, proto, out);
}